// Round 7
// baseline (133.887 us; speedup 1.0000x reference)
//
#include <hip/hip_runtime.h>

#define N_  16384
#define D_  128
#define M1_ 64
#define K_  8
#define LOG2E 1.44269504088896f

typedef short short8 __attribute__((ext_vector_type(8)));
typedef float f32x4  __attribute__((ext_vector_type(4)));

// pack two f32 -> one dword of 2x bf16 (RNE); no builtin on gfx950
__device__ __forceinline__ unsigned cvt_pk_bf16(float lo, float hi) {
    unsigned r;
    asm("v_cvt_pk_bf16_f32 %0, %1, %2" : "=v"(r) : "v"(lo), "v"(hi));
    return r;
}

// ---- prep: unchanged from verified round-2 (gather, coalesced stores) ----
__global__ void prep_all(const float* __restrict__ x,
                         const float* __restrict__ w1p, const float* __restrict__ b1p,
                         const float* __restrict__ w1n, const float* __restrict__ b1n,
                         const float* __restrict__ w2,  const float* __restrict__ b2,
                         const float* __restrict__ w3,
                         ushort* __restrict__ xbf, ushort* __restrict__ wbf,
                         float* __restrict__ bp, float* __restrict__ vv,
                         float* __restrict__ cv) {
    int bx = blockIdx.x;
    if (bx < 1024) {                                   // x cast+swizzle (gather)
        int g    = bx * 256 + threadIdx.x;             // slot id, 8 ushorts each
        int lane = g & 63;
        int ks   = (g >> 6) & 3;
        int n16  = g >> 8;
        int row   = n16 * 16 + (lane & 15);
        int dbase = ks * 32 + (lane >> 4) * 8;
        const float* xp = x + (size_t)row * D_ + dbase;
        float4 a = *(const float4*)xp;
        float4 b = *(const float4*)(xp + 4);
        union { unsigned u[4]; short8 s; } r;
        r.u[0] = cvt_pk_bf16(a.x, a.y);
        r.u[1] = cvt_pk_bf16(a.z, a.w);
        r.u[2] = cvt_pk_bf16(b.x, b.y);
        r.u[3] = cvt_pk_bf16(b.z, b.w);
        *(short8*)&xbf[(size_t)g * 8] = r.s;           // 16 B coalesced store
    } else if (bx < 1536) {                            // W mask+scale+cast+swizzle
        int g    = (bx - 1024) * 256 + threadIdx.x;
        int lane = g & 63;
        int t    = (g >> 6) & 15;                      // t = ks*4+mt
        int j    = g >> 10;
        int ks = t >> 2, mt = t & 3;
        int m     = mt * 16 + (lane & 15);
        int dbase = ks * 32 + (lane >> 4) * 8;
        const float* pp = w1p + ((size_t)(j * M1_ + m)) * D_ + dbase;
        const float* np = w1n + ((size_t)(j * M1_ + m)) * D_ + dbase;
        float4 p0 = *(const float4*)pp;
        float4 p1 = *(const float4*)(pp + 4);
        float4 n0 = *(const float4*)np;
        float4 n1 = *(const float4*)(np + 4);
        float f[8];
        f[0] = (p0.x - n0.x) * LOG2E; f[1] = (p0.y - n0.y) * LOG2E;
        f[2] = (p0.z - n0.z) * LOG2E; f[3] = (p0.w - n0.w) * LOG2E;
        f[4] = (p1.x - n1.x) * LOG2E; f[5] = (p1.y - n1.y) * LOG2E;
        f[6] = (p1.z - n1.z) * LOG2E; f[7] = (p1.w - n1.w) * LOG2E;
        #pragma unroll
        for (int e = 0; e < 8; e++)
            if (dbase + e == j) f[e] = 0.f;
        union { unsigned u[4]; short8 s; } r;
        r.u[0] = cvt_pk_bf16(f[0], f[1]);
        r.u[1] = cvt_pk_bf16(f[2], f[3]);
        r.u[2] = cvt_pk_bf16(f[4], f[5]);
        r.u[3] = cvt_pk_bf16(f[6], f[7]);
        *(short8*)&wbf[(size_t)g * 8] = r.s;           // 16 B coalesced store
    } else {                                           // b/v/c fold (f32)
        int idx = (bx - 1536) * 256 + threadIdx.x;     // idx < D_*M1_
        int j = idx >> 6, m = idx & 63;
        float v = 0.f;
        for (int k = 0; k < K_; k++) v += w3[j * K_ + k] * w2[k * M1_ + m];
        vv[idx] = v;
        bp[idx] = (b1p[idx] - b1n[idx]) * LOG2E;       // log2e-scaled bias (C-init)
        if (m == 0) {
            float c = 0.f;
            for (int k = 0; k < K_; k++) c += w3[j * K_ + k] * b2[k];
            cv[j] = c;
        }
    }
}

// ---- main: m-split (low regs, r6) + 2-deep acc pipeline (per-wave duty, r4).
// Evidence: VALU-busy-seconds is conserved at ~30 us across r0/r4/r6;
// duration = 30us / VALUBusy. r4 showed the pipeline raises per-wave duty
// 28%->34%; r6 showed the m-split keeps VGPR at 56. Combining should raise
// VALUBusy toward ~75% at r6's (or better) residency. NO min-waves clamp
// (r3 lesson); plain launch_bounds(256).
__global__ __launch_bounds__(256) void main_mfma(
    const ushort* __restrict__ xbf, const ushort* __restrict__ wbf,
    const float* __restrict__ bvec, const float* __restrict__ vvec,
    const float* __restrict__ cvec, float* __restrict__ out) {
    const int tid  = threadIdx.x;
    const int wave = tid >> 6, lane = tid & 63;
    const int quad = lane >> 4, col = lane & 15;
    const int mh   = wave & 1;                         // m-half (mt = mh*2 + {0,1})
    const int p    = wave >> 1;                        // n-subgroup within block
    const int j    = blockIdx.y;
    const int nblk = blockIdx.x;                       // fast dim -> XCD = nblk%8

    __shared__ float lds_pr[4][8][64];                 // [wave][st][lane], conflict-free

    // W fragments (A operand): this wave's 2 mt only
    short8 wfrag[2][4];                                // [ml][ks]
    const ushort* wg = wbf + (size_t)j * 8192 + lane * 8;
    #pragma unroll
    for (int ks = 0; ks < 4; ks++)
        #pragma unroll
        for (int ml = 0; ml < 2; ml++)
            wfrag[ml][ks] = *(const short8*)&wg[(ks * 4 + (mh * 2 + ml)) * 512];

    // epilogue constants (f32): lane's C-rows are m = (mh*2+ml)*16 + quad*4 + r
    f32x4 bias4[2], vm4[2];
    #pragma unroll
    for (int ml = 0; ml < 2; ml++) {
        const int mb = j * M1_ + (mh * 2 + ml) * 16 + quad * 4;
        bias4[ml] = *(const f32x4*)&bvec[mb];
        vm4[ml]   = *(const f32x4*)&vvec[mb];
    }
    const float cj = cvec[j];

    // x fragments (B operand): n16 = nblk*16 + p + st*2
    const ushort* xg = xbf + ((size_t)(nblk * 16 + p)) * 2048 + lane * 8;
    float* outp = out + (size_t)(nblk * 256 + p * 16 + col) * D_ + j;

    short8 abuf[2][4];
    #pragma unroll
    for (int ks = 0; ks < 4; ks++)
        abuf[0][ks] = *(const short8*)&xg[ks * 512];

    f32x4 acc[2][2];                                   // 2-deep accumulator sets
    float pr[8];                                       // per-st partial sums

    // epilogue for one acc set: s = 1/(1+2^-t); two independent fma chains
    #define EPILOGUE(A)                                                        \
        ({ float pa_ = 0.f, pb_ = 0.f;                                         \
           _Pragma("unroll")                                                   \
           for (int r_ = 0; r_ < 4; r_++) {                                    \
               float e0_ = __builtin_amdgcn_exp2f(-(A)[0][r_]);                \
               float e1_ = __builtin_amdgcn_exp2f(-(A)[1][r_]);                \
               float s0_ = __builtin_amdgcn_rcpf(1.0f + e0_);                  \
               float s1_ = __builtin_amdgcn_rcpf(1.0f + e1_);                  \
               pa_ = fmaf(s0_, vm4[0][r_], pa_);                               \
               pb_ = fmaf(s1_, vm4[1][r_], pb_);                               \
           }                                                                   \
           pa_ + pb_; })

    #pragma unroll
    for (int st = 0; st < 8; st++) {
        const int cur = st & 1, nxt = cur ^ 1;
        if (st < 7) {                                   // prefetch next subtile
            const ushort* xn = xg + (size_t)(st + 1) * 4096;
            #pragma unroll
            for (int ks = 0; ks < 4; ks++)
                abuf[nxt][ks] = *(const short8*)&xn[ks * 512];
        }

        // MFMA(st) -> acc[cur]; bias enters as C-in of the ks=0 rank
        #pragma unroll
        for (int ml = 0; ml < 2; ml++)
            acc[cur][ml] = __builtin_amdgcn_mfma_f32_16x16x32_bf16(
                               wfrag[ml][0], abuf[cur][0], bias4[ml], 0, 0, 0);
        #pragma unroll
        for (int ks = 1; ks < 4; ks++)
            #pragma unroll
            for (int ml = 0; ml < 2; ml++)
                acc[cur][ml] = __builtin_amdgcn_mfma_f32_16x16x32_bf16(
                                   wfrag[ml][ks], abuf[cur][ks], acc[cur][ml], 0, 0, 0);

        // epilogue(st-1) on the OTHER acc set — independent of MFMA(st)
        if (st >= 1)
            pr[st - 1] = EPILOGUE(acc[nxt]);
    }
    pr[7] = EPILOGUE(acc[1]);                           // st=7 used acc[1]
    #undef EPILOGUE

    // tail: combine m-halves across the wave pair via LDS, then cross-quad
    #pragma unroll
    for (int st = 0; st < 8; st++)
        lds_pr[wave][st][lane] = pr[st];
    __syncthreads();
    if (mh == 0) {
        #pragma unroll
        for (int st = 0; st < 8; st++)
            pr[st] += lds_pr[wave ^ 1][st][lane];
        #pragma unroll
        for (int st = 0; st < 8; st++)
            pr[st] += __shfl_xor(pr[st], 16);
        #pragma unroll
        for (int st = 0; st < 8; st++)
            pr[st] += __shfl_xor(pr[st], 32);
        if (quad == 0) {
            #pragma unroll
            for (int st = 0; st < 8; st++)
                outp[(size_t)st * 32 * D_] = pr[st] + cj;
        }
    }
}

// ---- fp32 fallback (workspace too small) ----
__global__ void fallback_kernel(const float* __restrict__ x,
                                const float* __restrict__ w1p, const float* __restrict__ b1p,
                                const float* __restrict__ w1n, const float* __restrict__ b1n,
                                const float* __restrict__ w2,  const float* __restrict__ b2,
                                const float* __restrict__ w3,  float* __restrict__ out) {
    int n = blockIdx.x, j = blockIdx.y, m = threadIdx.x;
    const float* xr = x + (size_t)n * D_;
    const float* wp = w1p + ((size_t)j * M1_ + m) * D_;
    const float* wn = w1n + ((size_t)j * M1_ + m) * D_;
    float acc = 0.f;
    for (int d = 0; d < D_; d++) {
        if (d == j) continue;
        acc += xr[d] * (wp[d] - wn[d]);
    }
    acc += b1p[j * M1_ + m] - b1n[j * M1_ + m];
    float h = 1.f / (1.f + __expf(-acc));
    float vmv = 0.f;
    for (int k = 0; k < K_; k++) vmv += w3[j * K_ + k] * w2[k * M1_ + m];
    float p = h * vmv;
    for (int off = 1; off < 64; off <<= 1) p += __shfl_xor(p, off);
    if (m == 0) {
        float c = 0.f;
        for (int k = 0; k < K_; k++) c += w3[j * K_ + k] * b2[k];
        out[(size_t)n * D_ + j] = p + c;
    }
}

extern "C" void kernel_launch(void* const* d_in, const int* in_sizes, int n_in,
                              void* d_out, int out_size, void* d_ws, size_t ws_size,
                              hipStream_t stream) {
    const float* x   = (const float*)d_in[0];
    const float* w1p = (const float*)d_in[1];
    const float* b1p = (const float*)d_in[2];
    const float* w1n = (const float*)d_in[3];
    const float* b1n = (const float*)d_in[4];
    const float* w2  = (const float*)d_in[5];
    const float* b2  = (const float*)d_in[6];
    const float* w3  = (const float*)d_in[7];
    float* out = (float*)d_out;

    const size_t off_x = 0;
    const size_t off_w = off_x + (size_t)N_ * D_ * 2;          // x bf16: 4 MB
    const size_t off_b = off_w + (size_t)D_ * M1_ * D_ * 2;    // W bf16: 2 MB
    const size_t off_v = off_b + (size_t)D_ * M1_ * 4;
    const size_t off_c = off_v + (size_t)D_ * M1_ * 4;
    const size_t need  = off_c + (size_t)D_ * 4;

    if (ws_size < need) {
        fallback_kernel<<<dim3(N_, D_), 64, 0, stream>>>(x, w1p, b1p, w1n, b1n, w2, b2, w3, out);
        return;
    }

    ushort* xbf = (ushort*)((char*)d_ws + off_x);
    ushort* wbf = (ushort*)((char*)d_ws + off_w);
    float*  bp  = (float*)((char*)d_ws + off_b);
    float*  vv  = (float*)((char*)d_ws + off_v);
    float*  cv  = (float*)((char*)d_ws + off_c);

    prep_all<<<1568, 256, 0, stream>>>(x, w1p, b1p, w1n, b1n, w2, b2, w3,
                                       xbf, wbf, bp, vv, cv);
    main_mfma<<<dim3(64, 128), 256, 0, stream>>>(xbf, wbf, bp, vv, cv, out);
}

// Round 8
// 124.968 us; speedup vs baseline: 1.0714x; 1.0714x over previous
//
#include <hip/hip_runtime.h>

#define N_  16384
#define D_  128
#define M1_ 64
#define K_  8
#define LOG2E 1.44269504088896f

typedef short short8 __attribute__((ext_vector_type(8)));
typedef float f32x4  __attribute__((ext_vector_type(4)));

// pack two f32 -> one dword of 2x bf16 (RNE); no builtin on gfx950
__device__ __forceinline__ unsigned cvt_pk_bf16(float lo, float hi) {
    unsigned r;
    asm("v_cvt_pk_bf16_f32 %0, %1, %2" : "=v"(r) : "v"(lo), "v"(hi));
    return r;
}

// ---- prep: unchanged from verified round-2 (gather, coalesced stores) ----
__global__ void prep_all(const float* __restrict__ x,
                         const float* __restrict__ w1p, const float* __restrict__ b1p,
                         const float* __restrict__ w1n, const float* __restrict__ b1n,
                         const float* __restrict__ w2,  const float* __restrict__ b2,
                         const float* __restrict__ w3,
                         ushort* __restrict__ xbf, ushort* __restrict__ wbf,
                         float* __restrict__ bp, float* __restrict__ vv,
                         float* __restrict__ cv) {
    int bx = blockIdx.x;
    if (bx < 1024) {                                   // x cast+swizzle (gather)
        int g    = bx * 256 + threadIdx.x;             // slot id, 8 ushorts each
        int lane = g & 63;
        int ks   = (g >> 6) & 3;
        int n16  = g >> 8;
        int row   = n16 * 16 + (lane & 15);
        int dbase = ks * 32 + (lane >> 4) * 8;
        const float* xp = x + (size_t)row * D_ + dbase;
        float4 a = *(const float4*)xp;
        float4 b = *(const float4*)(xp + 4);
        union { unsigned u[4]; short8 s; } r;
        r.u[0] = cvt_pk_bf16(a.x, a.y);
        r.u[1] = cvt_pk_bf16(a.z, a.w);
        r.u[2] = cvt_pk_bf16(b.x, b.y);
        r.u[3] = cvt_pk_bf16(b.z, b.w);
        *(short8*)&xbf[(size_t)g * 8] = r.s;           // 16 B coalesced store
    } else if (bx < 1536) {                            // W mask+scale+cast+swizzle
        int g    = (bx - 1024) * 256 + threadIdx.x;
        int lane = g & 63;
        int t    = (g >> 6) & 15;                      // t = ks*4+mt
        int j    = g >> 10;
        int ks = t >> 2, mt = t & 3;
        int m     = mt * 16 + (lane & 15);
        int dbase = ks * 32 + (lane >> 4) * 8;
        const float* pp = w1p + ((size_t)(j * M1_ + m)) * D_ + dbase;
        const float* np = w1n + ((size_t)(j * M1_ + m)) * D_ + dbase;
        float4 p0 = *(const float4*)pp;
        float4 p1 = *(const float4*)(pp + 4);
        float4 n0 = *(const float4*)np;
        float4 n1 = *(const float4*)(np + 4);
        float f[8];
        f[0] = (p0.x - n0.x) * LOG2E; f[1] = (p0.y - n0.y) * LOG2E;
        f[2] = (p0.z - n0.z) * LOG2E; f[3] = (p0.w - n0.w) * LOG2E;
        f[4] = (p1.x - n1.x) * LOG2E; f[5] = (p1.y - n1.y) * LOG2E;
        f[6] = (p1.z - n1.z) * LOG2E; f[7] = (p1.w - n1.w) * LOG2E;
        #pragma unroll
        for (int e = 0; e < 8; e++)
            if (dbase + e == j) f[e] = 0.f;
        union { unsigned u[4]; short8 s; } r;
        r.u[0] = cvt_pk_bf16(f[0], f[1]);
        r.u[1] = cvt_pk_bf16(f[2], f[3]);
        r.u[2] = cvt_pk_bf16(f[4], f[5]);
        r.u[3] = cvt_pk_bf16(f[6], f[7]);
        *(short8*)&wbf[(size_t)g * 8] = r.s;           // 16 B coalesced store
    } else {                                           // b/v/c fold (f32)
        int idx = (bx - 1536) * 256 + threadIdx.x;     // idx < D_*M1_
        int j = idx >> 6, m = idx & 63;
        float v = 0.f;
        for (int k = 0; k < K_; k++) v += w3[j * K_ + k] * w2[k * M1_ + m];
        vv[idx] = v;
        bp[idx] = (b1p[idx] - b1n[idx]) * LOG2E;       // log2e-scaled bias (C-init)
        if (m == 0) {
            float c = 0.f;
            for (int k = 0; k < K_; k++) c += w3[j * K_ + k] * b2[k];
            cv[j] = c;
        }
    }
}

// ---- main: r0's verified 52-us structure, epilogue swapped to 4-way
// combined reciprocal. Model (r0/r4/r6/r7 conservation law): trans pipe is
// saturated — 32 trans-ops/st (16 exp2 + 16 rcp) execute-serialize at ~8
// cyc/wave on the shared trans unit; VALUBusy caps at issue/execute ≈ 55%.
// 4-way rcp cuts trans/st 32->20 (exp2 is irreducible); numerics validated
// on-harness in round 1 (products bounded by 2^80).
__global__ __launch_bounds__(256) void main_mfma(
    const ushort* __restrict__ xbf, const ushort* __restrict__ wbf,
    const float* __restrict__ bvec, const float* __restrict__ vvec,
    const float* __restrict__ cvec, float* __restrict__ out) {
    const int tid  = threadIdx.x;
    const int wave = tid >> 6, lane = tid & 63;
    const int quad = lane >> 4, col = lane & 15;
    const int j    = blockIdx.y;
    const int nblk = blockIdx.x;                       // fast dim -> XCD = nblk%8

    // W fragments (A operand): one coalesced 16B/lane load each
    short8 wfrag[4][4];                                // [mt][ks]
    const ushort* wg = wbf + (size_t)j * 8192 + lane * 8;
    #pragma unroll
    for (int ks = 0; ks < 4; ks++)
        #pragma unroll
        for (int mt = 0; mt < 4; mt++)
            wfrag[mt][ks] = *(const short8*)&wg[(ks * 4 + mt) * 512];

    // epilogue constants (f32): lane's C-rows are m = mt*16 + quad*4 + r
    f32x4 bias4[4], vm4[4];
    #pragma unroll
    for (int mt = 0; mt < 4; mt++) {
        bias4[mt] = *(const f32x4*)&bvec[j * M1_ + mt * 16 + quad * 4];
        vm4[mt]   = *(const f32x4*)&vvec[j * M1_ + mt * 16 + quad * 4];
    }
    const float cj = cvec[j];

    // x fragments (B operand): n16 = nblk*32 + wave + st*4
    const ushort* xg = xbf + ((size_t)(nblk * 32 + wave)) * 2048 + lane * 8;
    float* outp = out + (size_t)(nblk * 512 + wave * 16 + col) * D_ + j;

    short8 abuf[2][4];
    #pragma unroll
    for (int ks = 0; ks < 4; ks++)
        abuf[0][ks] = *(const short8*)&xg[ks * 512];

    float pr[8];                                       // per-st partial sums

    #pragma unroll
    for (int st = 0; st < 8; st++) {
        const int cur = st & 1, nxt = cur ^ 1;
        if (st < 7) {                                   // prefetch next subtile
            const ushort* xn = xg + (size_t)(st + 1) * 8192;
            #pragma unroll
            for (int ks = 0; ks < 4; ks++)
                abuf[nxt][ks] = *(const short8*)&xn[ks * 512];
        }

        f32x4 acc[4];
        #pragma unroll
        for (int mt = 0; mt < 4; mt++) acc[mt] = bias4[mt];   // bias as C-init
        #pragma unroll
        for (int ks = 0; ks < 4; ks++)
            #pragma unroll
            for (int mt = 0; mt < 4; mt++)
                acc[mt] = __builtin_amdgcn_mfma_f32_16x16x32_bf16(
                              wfrag[mt][ks], abuf[cur][ks], acc[mt], 0, 0, 0);

        // sigma = 1/(1+2^-t): 4-way combined reciprocal per mt-quad.
        // trans/group: 4 exp2 + 1 rcp (was 8). full-rate/group: 17 (was 8).
        // two fma chains (mt parity) for dependency latency.
        float pa = 0.f, pb = 0.f;
        #pragma unroll
        for (int mt = 0; mt < 4; mt++) {
            float e0 = __builtin_amdgcn_exp2f(-acc[mt][0]);
            float e1 = __builtin_amdgcn_exp2f(-acc[mt][1]);
            float e2 = __builtin_amdgcn_exp2f(-acc[mt][2]);
            float e3 = __builtin_amdgcn_exp2f(-acc[mt][3]);
            float u0 = 1.f + e0, u1 = 1.f + e1, u2 = 1.f + e2, u3 = 1.f + e3;
            float p01 = u0 * u1, p23 = u2 * u3;
            float rc  = __builtin_amdgcn_rcpf(p01 * p23);
            float r01 = rc * p23, r23 = rc * p01;      // = 1/p01, 1/p23
            float& dst = (mt & 1) ? pb : pa;
            dst = fmaf(r01 * u1, vm4[mt][0], dst);     // u1/p01 = 1/u0... wait: r01*u1 = u1/(u0*u1) = 1/u0
            dst = fmaf(r01 * u0, vm4[mt][1], dst);
            dst = fmaf(r23 * u3, vm4[mt][2], dst);
            dst = fmaf(r23 * u2, vm4[mt][3], dst);
        }
        pr[st] = pa + pb;                               // NO shuffles/stores in loop
    }

    // tail: 16 independent cross-quad shuffles (pipelined), then 8 stores
    #pragma unroll
    for (int st = 0; st < 8; st++)
        pr[st] += __shfl_xor(pr[st], 16);
    #pragma unroll
    for (int st = 0; st < 8; st++)
        pr[st] += __shfl_xor(pr[st], 32);
    if (quad == 0) {
        #pragma unroll
        for (int st = 0; st < 8; st++)
            outp[(size_t)st * 64 * D_] = pr[st] + cj;
    }
}

// ---- fp32 fallback (workspace too small) ----
__global__ void fallback_kernel(const float* __restrict__ x,
                                const float* __restrict__ w1p, const float* __restrict__ b1p,
                                const float* __restrict__ w1n, const float* __restrict__ b1n,
                                const float* __restrict__ w2,  const float* __restrict__ b2,
                                const float* __restrict__ w3,  float* __restrict__ out) {
    int n = blockIdx.x, j = blockIdx.y, m = threadIdx.x;
    const float* xr = x + (size_t)n * D_;
    const float* wp = w1p + ((size_t)j * M1_ + m) * D_;
    const float* wn = w1n + ((size_t)j * M1_ + m) * D_;
    float acc = 0.f;
    for (int d = 0; d < D_; d++) {
        if (d == j) continue;
        acc += xr[d] * (wp[d] - wn[d]);
    }
    acc += b1p[j * M1_ + m] - b1n[j * M1_ + m];
    float h = 1.f / (1.f + __expf(-acc));
    float vmv = 0.f;
    for (int k = 0; k < K_; k++) vmv += w3[j * K_ + k] * w2[k * M1_ + m];
    float p = h * vmv;
    for (int off = 1; off < 64; off <<= 1) p += __shfl_xor(p, off);
    if (m == 0) {
        float c = 0.f;
        for (int k = 0; k < K_; k++) c += w3[j * K_ + k] * b2[k];
        out[(size_t)n * D_ + j] = p + c;
    }
}

extern "C" void kernel_launch(void* const* d_in, const int* in_sizes, int n_in,
                              void* d_out, int out_size, void* d_ws, size_t ws_size,
                              hipStream_t stream) {
    const float* x   = (const float*)d_in[0];
    const float* w1p = (const float*)d_in[1];
    const float* b1p = (const float*)d_in[2];
    const float* w1n = (const float*)d_in[3];
    const float* b1n = (const float*)d_in[4];
    const float* w2  = (const float*)d_in[5];
    const float* b2  = (const float*)d_in[6];
    const float* w3  = (const float*)d_in[7];
    float* out = (float*)d_out;

    const size_t off_x = 0;
    const size_t off_w = off_x + (size_t)N_ * D_ * 2;          // x bf16: 4 MB
    const size_t off_b = off_w + (size_t)D_ * M1_ * D_ * 2;    // W bf16: 2 MB
    const size_t off_v = off_b + (size_t)D_ * M1_ * 4;
    const size_t off_c = off_v + (size_t)D_ * M1_ * 4;
    const size_t need  = off_c + (size_t)D_ * 4;

    if (ws_size < need) {
        fallback_kernel<<<dim3(N_, D_), 64, 0, stream>>>(x, w1p, b1p, w1n, b1n, w2, b2, w3, out);
        return;
    }

    ushort* xbf = (ushort*)((char*)d_ws + off_x);
    ushort* wbf = (ushort*)((char*)d_ws + off_w);
    float*  bp  = (float*)((char*)d_ws + off_b);
    float*  vv  = (float*)((char*)d_ws + off_v);
    float*  cv  = (float*)((char*)d_ws + off_c);

    prep_all<<<1568, 256, 0, stream>>>(x, w1p, b1p, w1n, b1n, w2, b2, w3,
                                       xbf, wbf, bp, vv, cv);
    main_mfma<<<dim3(32, 128), 256, 0, stream>>>(xbf, wbf, bp, vv, cv, out);
}